// Round 8
// baseline (351.840 us; speedup 1.0000x reference)
//
#include <hip/hip_runtime.h>

#define NAG 12
#define NTH 4096
#define NEDGE 132
#define LDB 72    // bf16 row stride: 144 B = 16B-aligned, 36 dwords -> 2-way banks (free)

typedef __bf16 bf16_8 __attribute__((ext_vector_type(8)));
typedef float  f32x4  __attribute__((ext_vector_type(4)));

#define MFMA(a,b,c) __builtin_amdgcn_mfma_f32_16x16x32_bf16((a),(b),(c),0,0,0)

// ws layout:
//   frag region: 100 frags x 1024 B (64 lanes x 16 B)          [0, 102400)
//     0..3         : W_embed, nt
//     L = 4 + l*48 : We1a: L+nt*2+kh | We1b: L+8+nt*2+kh | We2: L+16+nt*2+kh
//                    Wh1: L+24+nt*4+ks | Wh2: L+40+nt*2+kh
//   bias region (fp32): float idx 25600 + ((l*4+w)*64+lane)*4  [102400, 110592)
//     w: 0=be1 1=be2 2=bh1 3=bh2 ; entry = f32x4 over nt
//   bx region  (fp32): float idx 27648 + l*64 + lane           [110592, 111104)
#define WS_FRAGS 100
#define WS_BIAS_F32 25600
#define WS_BX_F32   27648
#define WS_BYTES 111104

__device__ __forceinline__ float silu_f(float z) {
    float e = __expf(-z);
    return z * __builtin_amdgcn_rcpf(1.0f + e);
}

// B-frag from fp32 row-major [K][64]: lane holds B[kbase+q*8+j][n]  (verified R2)
__device__ __forceinline__ bf16_8 loadB64(const float* __restrict__ W, int kbase, int n, int q) {
    bf16_8 b;
    #pragma unroll
    for (int j = 0; j < 8; ++j) b[j] = (__bf16)W[(kbase + q*8 + j) * 64 + n];
    return b;
}

// A-frag from 8 consecutive fp32 (16B-aligned)
__device__ __forceinline__ bf16_8 packA8(const float* S) {
    f32x4 u = *(const f32x4*)S, v = *(const f32x4*)(S + 4);
    bf16_8 a;
    a[0]=(__bf16)u.x; a[1]=(__bf16)u.y; a[2]=(__bf16)u.z; a[3]=(__bf16)u.w;
    a[4]=(__bf16)v.x; a[5]=(__bf16)v.y; a[6]=(__bf16)v.z; a[7]=(__bf16)v.w;
    return a;
}

// ---- prep: pack weight B-fragments (bf16) + bias vectors (fp32) into d_ws ----
__global__ __launch_bounds__(64) void prep_frags(
    const float* __restrict__ W_embed, const float* __restrict__ We1,
    const float* __restrict__ We2, const float* __restrict__ Wh1,
    const float* __restrict__ Wh2,
    const float* __restrict__ be1, const float* __restrict__ be2,
    const float* __restrict__ bh1, const float* __restrict__ bh2,
    const float* __restrict__ bx, __bf16* __restrict__ wsb)
{
    const int f = blockIdx.x, lane = threadIdx.x;
    const int q = lane >> 4, n16 = lane & 15;
    float* wsf = (float*)wsb;
    if (f < WS_FRAGS) {
        const float* src; int kbase, nbase;
        if (f < 4) { src = W_embed; kbase = 0; nbase = f * 16; }
        else {
            int g0 = f - 4, l = g0 / 48, r = g0 % 48;
            if      (r < 8)  { int nt=r>>1, kh=r&1;            src = We1 + l*NEDGE*64; kbase = kh*32;      nbase = nt*16; }
            else if (r < 16) { int rr=r-8,  nt=rr>>1, kh=rr&1; src = We1 + l*NEDGE*64; kbase = 64 + kh*32; nbase = nt*16; }
            else if (r < 24) { int rr=r-16, nt=rr>>1, kh=rr&1; src = We2 + l*64*64;    kbase = kh*32;      nbase = nt*16; }
            else if (r < 40) { int rr=r-24, nt=rr>>2, ks=rr&3; src = Wh1 + l*128*64;   kbase = ks*32;      nbase = nt*16; }
            else             { int rr=r-40, nt=rr>>1, kh=rr&1; src = Wh2 + l*64*64;    kbase = kh*32;      nbase = nt*16; }
        }
        bf16_8 b = loadB64(src, kbase, nbase + n16, q);
        *(bf16_8*)(wsb + (size_t)f * 512 + lane * 8) = b;
    } else if (f < WS_FRAGS + 8) {
        int f2 = f - WS_FRAGS, l = f2 >> 2, w = f2 & 3;
        const float* src = (w == 0 ? be1 : w == 1 ? be2 : w == 2 ? bh1 : bh2) + l * 64;
        f32x4 v = { src[n16], src[16 + n16], src[32 + n16], src[48 + n16] };
        *(f32x4*)(wsf + WS_BIAS_F32 + ((size_t)(l*4 + w) * 64 + lane) * 4) = v;
    } else {
        #pragma unroll
        for (int l = 0; l < 2; ++l)
            wsf[WS_BX_F32 + l*64 + lane] = (n16 < 4) ? bx[l*4 + n16] : 0.f;
    }
}

template<bool WS>
__device__ __forceinline__ bf16_8 frg(const __bf16* __restrict__ wsb, int fid,
                                      const float* __restrict__ src, int kbase, int n, int lane) {
    if (WS) return *(const bf16_8*)(wsb + (size_t)fid * 512 + lane * 8);
    else    return loadB64(src, kbase, n, (lane >> 4));
}

// ---- main: ONE WAVE PER ENV, zero barriers ----
// __launch_bounds__(64,3): min 3 waves/EU -> VGPR cap ~170 -> 3 waves/SIMD.
// LDS 12.45 KB caps blocks/CU at 13 (3.25 waves/SIMD) so the compiler cannot
// overshoot to 4 waves/EU (the R3 spill disaster). R7 showed it self-selects
// 192 VGPR / 2 waves without this floor.
template<bool WS>
__global__ void __launch_bounds__(64, 3) egnn8(
    const float* __restrict__ h0, const float* __restrict__ x0,
    const float* __restrict__ W_embed, const float* __restrict__ b_embed,
    const float* __restrict__ We1, const float* __restrict__ be1,
    const float* __restrict__ We2, const float* __restrict__ be2,
    const float* __restrict__ Wx, const float* __restrict__ bx,
    const float* __restrict__ Wh1, const float* __restrict__ bh1,
    const float* __restrict__ Wh2, const float* __restrict__ bh2,
    const float* __restrict__ w_act, const float* __restrict__ log_std,
    const __bf16* __restrict__ wsb, float* __restrict__ out)
{
    // 12448 B total -> 13 blocks/CU by LDS
    __shared__ __align__(16) __bf16 sh  [NAG * LDB];   // h (bf16 copy; fp32 residual in regs)
    __shared__ __align__(16) __bf16 sHa [NAG * LDB];   // h@We1[0:64]+be1; later t1
    __shared__ __align__(16) __bf16 sHb [NAG * LDB];   // h@We1[64:128]; later agg (bf16)
    __shared__ __align__(16) __bf16 mst [16 * LDB];    // per-tile m staging
    __shared__ __align__(16) float  sx  [NAG * 16];    // coords [i][d*4+v]
    __shared__ __align__(16) float  sRad[NEDGE * 4];
    __shared__ __align__(16) __bf16 sWcB[NEDGE * 4];   // coord weights (bf16)
    __shared__ __align__(16) float  sWb [4 * 64];      // We1 radial rows (fp32)

    const int lane = threadIdx.x;
    const int q = lane >> 4, n16 = lane & 15;
    const int rowA = (n16 < NAG) ? n16 : (NAG - 1);
    const int env  = blockIdx.x;
    const float* wsf = (const float*)wsb;

    // ---- constant log-prob half of the output: off the dependence tail ----
    if (lane < NAG * 3) {
        int d = lane % 3;
        out[NTH * NAG * 3 + env * (NAG*3) + lane] = -log_std[d] - 0.9189385332046727f;
    }

    // ---- load x ----
    #pragma unroll
    for (int p = 0; p < 3; ++p) {
        int idx = p * 64 + lane;
        if (idx < NAG * 12) sx[(idx / 12) * 16 + idx % 12] = x0[env * NAG * 12 + idx];
    }

    // ---- embed: h = h0 @ W_embed + b; residual kept in C-frag registers (fp32) ----
    f32x4 hC[4];
    {
        const float* hp = h0 + (env * NAG + rowA) * 32 + q * 8;
        bf16_8 a = packA8(hp);
        #pragma unroll
        for (int nt = 0; nt < 4; ++nt) {
            bf16_8 b = frg<WS>(wsb, nt, W_embed, 0, nt*16 + n16, lane);
            f32x4 acc = {0.f,0.f,0.f,0.f};
            acc = MFMA(a, b, acc);
            float bias = b_embed[nt*16 + n16];
            #pragma unroll
            for (int r = 0; r < 4; ++r) acc[r] += bias;
            hC[nt] = acc;
        }
        #pragma unroll
        for (int nt = 0; nt < 4; ++nt)
            #pragma unroll
            for (int r = 0; r < 4; ++r) {
                int row = q*4 + r;
                if (row < NAG) sh[row*LDB + nt*16 + n16] = (__bf16)hC[nt][r];
            }
    }

    #pragma unroll 1
    for (int l = 0; l < 2; ++l) {
        const float* We1l = We1 + l * NEDGE * 64;
        const float* be1l = be1 + l * 64;
        const float* be2l = be2 + l * 64;
        const float* Wxl  = Wx  + l * 64 * 4;
        const float* bxl  = bx  + l * 4;
        const float* We2l = We2 + l * 64 * 64;
        const float* Wh1l = Wh1 + l * 128 * 64;
        const float* bh1l = bh1 + l * 64;
        const float* Wh2l = Wh2 + l * 64 * 64;
        const float* bh2l = bh2 + l * 64;
        const int L = 4 + l * 48;

        f32x4 be1q, be2q, bh1q, bh2q;   // [nt]
        float bxv;
        if (WS) {
            const float* bb = wsf + WS_BIAS_F32 + (size_t)(l*4) * 256 + lane * 4;
            be1q = *(const f32x4*)(bb);
            be2q = *(const f32x4*)(bb + 256);
            bh1q = *(const f32x4*)(bb + 512);
            bh2q = *(const f32x4*)(bb + 768);
            bxv  = wsf[WS_BX_F32 + l*64 + lane];
        } else {
            #pragma unroll
            for (int nt = 0; nt < 4; ++nt) {
                be1q[nt] = be1l[nt*16+n16]; be2q[nt] = be2l[nt*16+n16];
                bh1q[nt] = bh1l[nt*16+n16]; bh2q[nt] = bh2l[nt*16+n16];
            }
            bxv = (n16 < 4) ? bxl[n16] : 0.f;
        }

        // ---- Stage A: Ha = h@We1a + be1, Hb = h@We1b (bf16 LDS); radial; We1c stage ----
        {
            bf16_8 a0 = *(const bf16_8*)(sh + rowA*LDB + q*8);
            bf16_8 a1 = *(const bf16_8*)(sh + rowA*LDB + 32 + q*8);
            #pragma unroll
            for (int nt = 0; nt < 4; ++nt) {
                bf16_8 b0 = frg<WS>(wsb, L+nt*2+0,   We1l, 0,  nt*16+n16, lane);
                bf16_8 b1 = frg<WS>(wsb, L+nt*2+1,   We1l, 32, nt*16+n16, lane);
                bf16_8 c0 = frg<WS>(wsb, L+8+nt*2+0, We1l, 64, nt*16+n16, lane);
                bf16_8 c1 = frg<WS>(wsb, L+8+nt*2+1, We1l, 96, nt*16+n16, lane);
                f32x4 aA = {0.f,0.f,0.f,0.f}, aB = {0.f,0.f,0.f,0.f};
                aA = MFMA(a0, b0, aA); aA = MFMA(a1, b1, aA);
                aB = MFMA(a0, c0, aB); aB = MFMA(a1, c1, aB);
                #pragma unroll
                for (int r = 0; r < 4; ++r) {
                    int row = q*4 + r;
                    if (row < NAG) {
                        sHa[row*LDB + nt*16+n16] = (__bf16)(aA[r] + be1q[nt]);
                        sHb[row*LDB + nt*16+n16] = (__bf16)aB[r];
                    }
                }
            }
        }
        #pragma unroll
        for (int p = 0; p < 4; ++p) sWb[p*64 + lane] = We1l[(128+p)*64 + lane];
        #pragma unroll
        for (int p = 0; p < 9; ++p) {
            int idx = p * 64 + lane;
            if (idx < NEDGE * 4) {
                int e = idx >> 2, v = idx & 3;
                int i = e / 11, jj = e - i * 11, j = jj + (jj >= i);
                float r = 0.f;
                #pragma unroll
                for (int d = 0; d < 3; ++d) {
                    float df = sx[i*16 + d*4 + v] - sx[j*16 + d*4 + v];
                    r += df * df;
                }
                sRad[idx] = r;
            }
        }

        // ---- Edge stage: 9 M-tiles; m via per-tile LDS staging (wave-private) ----
        float agg[NAG];
        #pragma unroll
        for (int i = 0; i < NAG; ++i) agg[i] = 0.f;
        bf16_8 w2f[4][2], wxf[2];
        #pragma unroll
        for (int nt = 0; nt < 4; ++nt) {
            w2f[nt][0] = frg<WS>(wsb, L+16+nt*2+0, We2l, 0,  nt*16+n16, lane);
            w2f[nt][1] = frg<WS>(wsb, L+16+nt*2+1, We2l, 32, nt*16+n16, lane);
        }
        #pragma unroll
        for (int kh = 0; kh < 2; ++kh) {   // Wx B-frag, cols 4..15 zero-padded
            bf16_8 b;
            #pragma unroll
            for (int j2 = 0; j2 < 8; ++j2)
                b[j2] = (n16 < 4) ? (__bf16)Wxl[(kh*32 + q*8 + j2)*4 + n16] : (__bf16)0.f;
            wxf[kh] = b;
        }

        #pragma unroll
        for (int t = 0; t < 9; ++t) {
            const int e  = t*16 + n16;
            const int ec = (e < NEDGE) ? e : (NEDGE - 1);
            const int i  = ec / 11;
            const int jj = ec - i * 11;
            const int j  = jj + (jj >= i);
            const f32x4 rd = *(const f32x4*)(sRad + ec * 4);
            // s1 A-frags built directly in A-layout
            bf16_8 af0, af1;
            #pragma unroll
            for (int kh = 0; kh < 2; ++kh) {
                const int cb = kh*32 + q*8;
                bf16_8 ha = *(const bf16_8*)(sHa + i*LDB + cb);
                bf16_8 hb = *(const bf16_8*)(sHb + j*LDB + cb);
                f32x4 wr0 = {0.f,0.f,0.f,0.f}, wr1 = {0.f,0.f,0.f,0.f};
                #pragma unroll
                for (int v = 0; v < 4; ++v) {
                    f32x4 wa = *(const f32x4*)(sWb + v*64 + cb);        // loop-invariant
                    f32x4 wb = *(const f32x4*)(sWb + v*64 + cb + 4);
                    wr0 += rd[v] * wa; wr1 += rd[v] * wb;
                }
                bf16_8 a;
                #pragma unroll
                for (int c = 0; c < 4; ++c)
                    a[c]   = (__bf16)silu_f((float)ha[c]   + (float)hb[c]   + wr0[c]);
                #pragma unroll
                for (int c = 0; c < 4; ++c)
                    a[4+c] = (__bf16)silu_f((float)ha[4+c] + (float)hb[4+c] + wr1[c]);
                if (kh == 0) af0 = a; else af1 = a;
            }
            // m = silu(s1@We2 + be2) -> bf16 staging
            #pragma unroll
            for (int nt = 0; nt < 4; ++nt) {
                f32x4 acc = {0.f,0.f,0.f,0.f};
                acc = MFMA(af0, w2f[nt][0], acc);
                acc = MFMA(af1, w2f[nt][1], acc);
                #pragma unroll
                for (int r = 0; r < 4; ++r)
                    mst[(q*4+r)*LDB + nt*16+n16] = (__bf16)silu_f(acc[r] + be2q[nt]);
            }
            // wc = m@Wx + bx via MFMA (N=4 real cols)
            {
                bf16_8 aw0 = *(const bf16_8*)(mst + n16*LDB + q*8);
                bf16_8 aw1 = *(const bf16_8*)(mst + n16*LDB + 32 + q*8);
                f32x4 acc = {0.f,0.f,0.f,0.f};
                acc = MFMA(aw0, wxf[0], acc);
                acc = MFMA(aw1, wxf[1], acc);
                if (n16 < 4) {
                    #pragma unroll
                    for (int r = 0; r < 4; ++r) {
                        int row = t*16 + q*4 + r;
                        if (row < NEDGE) sWcB[row*4 + n16] = (__bf16)(acc[r] + bxv);
                    }
                }
            }
            // agg: lane = col; node index compile-time via full unroll
            {
                const int elim = (t == 8) ? 4 : 16;
                #pragma unroll
                for (int el = 0; el < 16; ++el) {
                    if (el < elim) {
                        const int node = (t*16 + el) / 11;
                        agg[node] += (float)mst[el*LDB + lane];
                    }
                }
            }
        }
        // agg -> sHb (Hb dead after edge loop)
        #pragma unroll
        for (int i = 0; i < NAG; ++i) sHb[i*LDB + lane] = (__bf16)agg[i];

        // ---- xacc (pre-update x reads) ----
        float xn[3];
        #pragma unroll
        for (int p = 0; p < 3; ++p) {
            int idx = p*64 + lane;
            float res = 0.f;
            if (idx < 144) {
                int xi = idx / 12, dv = idx % 12, v = dv & 3;
                float xiv = sx[xi*16 + dv];
                float acc = 0.f;
                #pragma unroll
                for (int j2 = 0; j2 < NAG; ++j2) {
                    int e = xi*11 + j2 - (j2 > xi ? 1 : 0);
                    e = (e < NEDGE) ? e : (NEDGE - 1);
                    float term = (xiv - sx[j2*16 + dv]) * (float)sWcB[e*4 + v];
                    acc += (j2 == xi) ? 0.f : term;
                }
                res = xiv + acc * (1.0f / 11.0f);
            }
            xn[p] = res;
        }
        // ---- Wh1: t1 = silu([h,agg]@Wh1 + bh1) -> sHa (reuse) ----
        {
            bf16_8 ah0 = *(const bf16_8*)(sh  + rowA*LDB + q*8);
            bf16_8 ah1 = *(const bf16_8*)(sh  + rowA*LDB + 32 + q*8);
            bf16_8 ag0 = *(const bf16_8*)(sHb + rowA*LDB + q*8);
            bf16_8 ag1 = *(const bf16_8*)(sHb + rowA*LDB + 32 + q*8);
            #pragma unroll
            for (int nt = 0; nt < 4; ++nt) {
                f32x4 acc = {0.f,0.f,0.f,0.f};
                acc = MFMA(ah0, frg<WS>(wsb, L+24+nt*4+0, Wh1l, 0,  nt*16+n16, lane), acc);
                acc = MFMA(ah1, frg<WS>(wsb, L+24+nt*4+1, Wh1l, 32, nt*16+n16, lane), acc);
                acc = MFMA(ag0, frg<WS>(wsb, L+24+nt*4+2, Wh1l, 64, nt*16+n16, lane), acc);
                acc = MFMA(ag1, frg<WS>(wsb, L+24+nt*4+3, Wh1l, 96, nt*16+n16, lane), acc);
                #pragma unroll
                for (int r = 0; r < 4; ++r) {
                    int row = q*4 + r;
                    if (row < NAG) sHa[row*LDB + nt*16+n16] = (__bf16)silu_f(acc[r] + bh1q[nt]);
                }
            }
        }
        // ---- x writeback; Wh2: h += t1@Wh2 + bh2 (register residual) ----
        #pragma unroll
        for (int p = 0; p < 3; ++p) {
            int idx = p*64 + lane;
            if (idx < 144) sx[(idx/12)*16 + idx%12] = xn[p];
        }
        {
            bf16_8 at0 = *(const bf16_8*)(sHa + rowA*LDB + q*8);
            bf16_8 at1 = *(const bf16_8*)(sHa + rowA*LDB + 32 + q*8);
            #pragma unroll
            for (int nt = 0; nt < 4; ++nt) {
                f32x4 acc = {0.f,0.f,0.f,0.f};
                acc = MFMA(at0, frg<WS>(wsb, L+40+nt*2+0, Wh2l, 0,  nt*16+n16, lane), acc);
                acc = MFMA(at1, frg<WS>(wsb, L+40+nt*2+1, Wh2l, 32, nt*16+n16, lane), acc);
                #pragma unroll
                for (int r = 0; r < 4; ++r) hC[nt][r] += acc[r] + bh2q[nt];
            }
            #pragma unroll
            for (int nt = 0; nt < 4; ++nt)
                #pragma unroll
                for (int r = 0; r < 4; ++r) {
                    int row = q*4 + r;
                    if (row < NAG) sh[row*LDB + nt*16+n16] = (__bf16)hC[nt][r];
                }
        }
    }

    // ---- epilogue: mu only (log-prob half already written) ----
    if (lane < NAG * 3) {
        int i = lane / 3, d = lane - i * 3;
        float mu = 0.f;
        #pragma unroll
        for (int v = 0; v < 4; ++v) mu += sx[i*16 + d*4 + v] * w_act[v];
        out[env * (NAG*3) + lane] = mu;
    }
}

extern "C" void kernel_launch(void* const* d_in, const int* in_sizes, int n_in,
                              void* d_out, int out_size, void* d_ws, size_t ws_size,
                              hipStream_t stream) {
    // inputs: h0,x0,W_embed,b_embed,We1,be1,We2,be2,Wx,bx,Wh1,bh1,Wh2,bh2,w_act,log_std,row,col
    const float* h0   = (const float*)d_in[0];
    const float* x0   = (const float*)d_in[1];
    const float* Wem  = (const float*)d_in[2];
    const float* bem  = (const float*)d_in[3];
    const float* We1  = (const float*)d_in[4];
    const float* be1  = (const float*)d_in[5];
    const float* We2  = (const float*)d_in[6];
    const float* be2  = (const float*)d_in[7];
    const float* Wx   = (const float*)d_in[8];
    const float* bx   = (const float*)d_in[9];
    const float* Wh1  = (const float*)d_in[10];
    const float* bh1  = (const float*)d_in[11];
    const float* Wh2  = (const float*)d_in[12];
    const float* bh2  = (const float*)d_in[13];
    const float* wact = (const float*)d_in[14];
    const float* lstd = (const float*)d_in[15];
    float* out = (float*)d_out;

    if (ws_size >= (size_t)WS_BYTES) {
        prep_frags<<<dim3(WS_FRAGS + 9), dim3(64), 0, stream>>>(
            Wem, We1, We2, Wh1, Wh2, be1, be2, bh1, bh2, bx, (__bf16*)d_ws);
        egnn8<true><<<dim3(NTH), dim3(64), 0, stream>>>(
            h0, x0, Wem, bem, We1, be1, We2, be2, Wx, bx,
            Wh1, bh1, Wh2, bh2, wact, lstd, (const __bf16*)d_ws, out);
    } else {
        egnn8<false><<<dim3(NTH), dim3(64), 0, stream>>>(
            h0, x0, Wem, bem, We1, be1, We2, be2, Wx, bx,
            Wh1, bh1, Wh2, bh2, wact, lstd, nullptr, out);
    }
}

// Round 9
// 239.639 us; speedup vs baseline: 1.4682x; 1.4682x over previous
//
#include <hip/hip_runtime.h>

#define NAG 12
#define NTH 4096
#define NEDGE 132
#define LDB 72    // bf16 node-buffer row stride: 144 B, 16B-aligned, 2-way banks (free)
#define LDT 20    // mstT col stride (bf16): 40 B -> 8B-aligned b64, low-conflict

typedef __bf16 bf16_8 __attribute__((ext_vector_type(8)));
typedef __bf16 bf16_4 __attribute__((ext_vector_type(4)));
typedef float  f32x4  __attribute__((ext_vector_type(4)));

#define MFMA(a,b,c) __builtin_amdgcn_mfma_f32_16x16x32_bf16((a),(b),(c),0,0,0)

// ws layout:
//   frag region: 100 frags x 1024 B (64 lanes x 16 B)          [0, 102400)
//     0..3         : W_embed, nt
//     L = 4 + l*48 : We1a: L+nt*2+kh | We1b: L+8+nt*2+kh | We2: L+16+nt*2+kh
//                    Wh1: L+24+nt*4+ks | Wh2: L+40+nt*2+kh
//   bias region (fp32): float idx 25600 + ((l*4+w)*64+lane)*4  [102400, 110592)
//     w: 0=be1 1=be2 2=bh1 3=bh2 ; entry = f32x4 over nt
//   bx region  (fp32): float idx 27648 + l*64 + lane           [110592, 111104)
#define WS_FRAGS 100
#define WS_BIAS_F32 25600
#define WS_BX_F32   27648
#define WS_BYTES 111104

__device__ __forceinline__ float silu_f(float z) {
    float e = __expf(-z);
    return z * __builtin_amdgcn_rcpf(1.0f + e);
}

// B-frag from fp32 row-major [K][64]: lane holds B[kbase+q*8+j][n]  (verified R2)
__device__ __forceinline__ bf16_8 loadB64(const float* __restrict__ W, int kbase, int n, int q) {
    bf16_8 b;
    #pragma unroll
    for (int j = 0; j < 8; ++j) b[j] = (__bf16)W[(kbase + q*8 + j) * 64 + n];
    return b;
}

// A-frag from 8 consecutive fp32 (16B-aligned)
__device__ __forceinline__ bf16_8 packA8(const float* S) {
    f32x4 u = *(const f32x4*)S, v = *(const f32x4*)(S + 4);
    bf16_8 a;
    a[0]=(__bf16)u.x; a[1]=(__bf16)u.y; a[2]=(__bf16)u.z; a[3]=(__bf16)u.w;
    a[4]=(__bf16)v.x; a[5]=(__bf16)v.y; a[6]=(__bf16)v.z; a[7]=(__bf16)v.w;
    return a;
}

// ---- prep: pack weight B-fragments (bf16) + bias vectors (fp32) into d_ws ----
__global__ __launch_bounds__(64) void prep_frags(
    const float* __restrict__ W_embed, const float* __restrict__ We1,
    const float* __restrict__ We2, const float* __restrict__ Wh1,
    const float* __restrict__ Wh2,
    const float* __restrict__ be1, const float* __restrict__ be2,
    const float* __restrict__ bh1, const float* __restrict__ bh2,
    const float* __restrict__ bx, __bf16* __restrict__ wsb)
{
    const int f = blockIdx.x, lane = threadIdx.x;
    const int q = lane >> 4, n16 = lane & 15;
    float* wsf = (float*)wsb;
    if (f < WS_FRAGS) {
        const float* src; int kbase, nbase;
        if (f < 4) { src = W_embed; kbase = 0; nbase = f * 16; }
        else {
            int g0 = f - 4, l = g0 / 48, r = g0 % 48;
            if      (r < 8)  { int nt=r>>1, kh=r&1;            src = We1 + l*NEDGE*64; kbase = kh*32;      nbase = nt*16; }
            else if (r < 16) { int rr=r-8,  nt=rr>>1, kh=rr&1; src = We1 + l*NEDGE*64; kbase = 64 + kh*32; nbase = nt*16; }
            else if (r < 24) { int rr=r-16, nt=rr>>1, kh=rr&1; src = We2 + l*64*64;    kbase = kh*32;      nbase = nt*16; }
            else if (r < 40) { int rr=r-24, nt=rr>>2, ks=rr&3; src = Wh1 + l*128*64;   kbase = ks*32;      nbase = nt*16; }
            else             { int rr=r-40, nt=rr>>1, kh=rr&1; src = Wh2 + l*64*64;    kbase = kh*32;      nbase = nt*16; }
        }
        bf16_8 b = loadB64(src, kbase, nbase + n16, q);
        *(bf16_8*)(wsb + (size_t)f * 512 + lane * 8) = b;
    } else if (f < WS_FRAGS + 8) {
        int f2 = f - WS_FRAGS, l = f2 >> 2, w = f2 & 3;
        const float* src = (w == 0 ? be1 : w == 1 ? be2 : w == 2 ? bh1 : bh2) + l * 64;
        f32x4 v = { src[n16], src[16 + n16], src[32 + n16], src[48 + n16] };
        *(f32x4*)(wsf + WS_BIAS_F32 + ((size_t)(l*4 + w) * 64 + lane) * 4) = v;
    } else {
        #pragma unroll
        for (int l = 0; l < 2; ++l)
            wsf[WS_BX_F32 + l*64 + lane] = (n16 < 4) ? bx[l*4 + n16] : 0.f;
    }
}

template<bool WS>
__device__ __forceinline__ bf16_8 frg(const __bf16* __restrict__ wsb, int fid,
                                      const float* __restrict__ src, int kbase, int n, int lane) {
    if (WS) return *(const bf16_8*)(wsb + (size_t)fid * 512 + lane * 8);
    else    return loadB64(src, kbase, n, (lane >> 4));
}

// ---- main: ONE WAVE PER ENV, zero barriers, mstT double-buffered+transposed ----
// NOTE (R3/R4/R8): occupancy-hint attributes (launch_bounds min, waves_per_eu)
// make the gfx950 allocator overshoot (64/84 VGPR) -> HBM spill storms. Leave
// the allocator alone; it self-selects ~192 VGPR / 2 waves/SIMD spill-free.
template<bool WS>
__global__ void __launch_bounds__(64) egnn9(
    const float* __restrict__ h0, const float* __restrict__ x0,
    const float* __restrict__ W_embed, const float* __restrict__ b_embed,
    const float* __restrict__ We1, const float* __restrict__ be1,
    const float* __restrict__ We2, const float* __restrict__ be2,
    const float* __restrict__ Wx, const float* __restrict__ bx,
    const float* __restrict__ Wh1, const float* __restrict__ bh1,
    const float* __restrict__ Wh2, const float* __restrict__ bh2,
    const float* __restrict__ w_act, const float* __restrict__ log_std,
    const __bf16* __restrict__ wsb, float* __restrict__ out)
{
    // 15264 B total -> 10 blocks/CU by LDS
    __shared__ __align__(16) __bf16 sh  [NAG * LDB];   // h (bf16 copy; fp32 residual in regs)
    __shared__ __align__(16) __bf16 sHa [NAG * LDB];   // h@We1[0:64]+be1; later t1
    __shared__ __align__(16) __bf16 sHb [NAG * LDB];   // h@We1[64:128]; later agg (bf16)
    __shared__ __align__(16) __bf16 mstT[2][64 * LDT]; // m staging, TRANSPOSED [col][row], dbuf
    __shared__ __align__(16) float  sx  [NAG * 16];    // coords [i][d*4+v]
    __shared__ __align__(16) float  sRad[NEDGE * 4];
    __shared__ __align__(16) __bf16 sWcB[NEDGE * 4];   // coord weights (bf16)
    __shared__ __align__(16) float  sWb [4 * 64];      // We1 radial rows (fp32)

    const int lane = threadIdx.x;
    const int q = lane >> 4, n16 = lane & 15;
    const int rowA = (n16 < NAG) ? n16 : (NAG - 1);
    const int env  = blockIdx.x;
    const float* wsf = (const float*)wsb;

    // ---- constant log-prob half of the output: off the dependence tail ----
    if (lane < NAG * 3) {
        int d = lane % 3;
        out[NTH * NAG * 3 + env * (NAG*3) + lane] = -log_std[d] - 0.9189385332046727f;
    }

    // ---- load x ----
    #pragma unroll
    for (int p = 0; p < 3; ++p) {
        int idx = p * 64 + lane;
        if (idx < NAG * 12) sx[(idx / 12) * 16 + idx % 12] = x0[env * NAG * 12 + idx];
    }

    // ---- embed: h = h0 @ W_embed + b; residual kept in C-frag registers (fp32) ----
    f32x4 hC[4];
    {
        const float* hp = h0 + (env * NAG + rowA) * 32 + q * 8;
        bf16_8 a = packA8(hp);
        #pragma unroll
        for (int nt = 0; nt < 4; ++nt) {
            bf16_8 b = frg<WS>(wsb, nt, W_embed, 0, nt*16 + n16, lane);
            f32x4 acc = {0.f,0.f,0.f,0.f};
            acc = MFMA(a, b, acc);
            float bias = b_embed[nt*16 + n16];
            #pragma unroll
            for (int r = 0; r < 4; ++r) acc[r] += bias;
            hC[nt] = acc;
        }
        #pragma unroll
        for (int nt = 0; nt < 4; ++nt)
            #pragma unroll
            for (int r = 0; r < 4; ++r) {
                int row = q*4 + r;
                if (row < NAG) sh[row*LDB + nt*16 + n16] = (__bf16)hC[nt][r];
            }
    }

    #pragma unroll 1
    for (int l = 0; l < 2; ++l) {
        const float* We1l = We1 + l * NEDGE * 64;
        const float* be1l = be1 + l * 64;
        const float* be2l = be2 + l * 64;
        const float* Wxl  = Wx  + l * 64 * 4;
        const float* bxl  = bx  + l * 4;
        const float* We2l = We2 + l * 64 * 64;
        const float* Wh1l = Wh1 + l * 128 * 64;
        const float* bh1l = bh1 + l * 64;
        const float* Wh2l = Wh2 + l * 64 * 64;
        const float* bh2l = bh2 + l * 64;
        const int L = 4 + l * 48;

        f32x4 be1q, be2q, bh1q, bh2q;   // [nt]
        float bxv;
        if (WS) {
            const float* bb = wsf + WS_BIAS_F32 + (size_t)(l*4) * 256 + lane * 4;
            be1q = *(const f32x4*)(bb);
            be2q = *(const f32x4*)(bb + 256);
            bh1q = *(const f32x4*)(bb + 512);
            bh2q = *(const f32x4*)(bb + 768);
            bxv  = wsf[WS_BX_F32 + l*64 + lane];
        } else {
            #pragma unroll
            for (int nt = 0; nt < 4; ++nt) {
                be1q[nt] = be1l[nt*16+n16]; be2q[nt] = be2l[nt*16+n16];
                bh1q[nt] = bh1l[nt*16+n16]; bh2q[nt] = bh2l[nt*16+n16];
            }
            bxv = (n16 < 4) ? bxl[n16] : 0.f;
        }

        // ---- Stage A: Ha = h@We1a + be1, Hb = h@We1b (bf16 LDS); radial; We1c stage ----
        {
            bf16_8 a0 = *(const bf16_8*)(sh + rowA*LDB + q*8);
            bf16_8 a1 = *(const bf16_8*)(sh + rowA*LDB + 32 + q*8);
            #pragma unroll
            for (int nt = 0; nt < 4; ++nt) {
                bf16_8 b0 = frg<WS>(wsb, L+nt*2+0,   We1l, 0,  nt*16+n16, lane);
                bf16_8 b1 = frg<WS>(wsb, L+nt*2+1,   We1l, 32, nt*16+n16, lane);
                bf16_8 c0 = frg<WS>(wsb, L+8+nt*2+0, We1l, 64, nt*16+n16, lane);
                bf16_8 c1 = frg<WS>(wsb, L+8+nt*2+1, We1l, 96, nt*16+n16, lane);
                f32x4 aA = {0.f,0.f,0.f,0.f}, aB = {0.f,0.f,0.f,0.f};
                aA = MFMA(a0, b0, aA); aA = MFMA(a1, b1, aA);
                aB = MFMA(a0, c0, aB); aB = MFMA(a1, c1, aB);
                #pragma unroll
                for (int r = 0; r < 4; ++r) {
                    int row = q*4 + r;
                    if (row < NAG) {
                        sHa[row*LDB + nt*16+n16] = (__bf16)(aA[r] + be1q[nt]);
                        sHb[row*LDB + nt*16+n16] = (__bf16)aB[r];
                    }
                }
            }
        }
        #pragma unroll
        for (int p = 0; p < 4; ++p) sWb[p*64 + lane] = We1l[(128+p)*64 + lane];
        #pragma unroll
        for (int p = 0; p < 9; ++p) {
            int idx = p * 64 + lane;
            if (idx < NEDGE * 4) {
                int e = idx >> 2, v = idx & 3;
                int i = e / 11, jj = e - i * 11, j = jj + (jj >= i);
                float r = 0.f;
                #pragma unroll
                for (int d = 0; d < 3; ++d) {
                    float df = sx[i*16 + d*4 + v] - sx[j*16 + d*4 + v];
                    r += df * df;
                }
                sRad[idx] = r;
            }
        }

        // ---- Edge stage: 9 M-tiles; transposed + double-buffered m staging ----
        float agg[NAG];
        #pragma unroll
        for (int i = 0; i < NAG; ++i) agg[i] = 0.f;
        bf16_8 w2f[4][2], wxf[2];
        #pragma unroll
        for (int nt = 0; nt < 4; ++nt) {
            w2f[nt][0] = frg<WS>(wsb, L+16+nt*2+0, We2l, 0,  nt*16+n16, lane);
            w2f[nt][1] = frg<WS>(wsb, L+16+nt*2+1, We2l, 32, nt*16+n16, lane);
        }
        #pragma unroll
        for (int kh = 0; kh < 2; ++kh) {   // Wx B-frag, cols 4..15 zero-padded
            bf16_8 b;
            #pragma unroll
            for (int j2 = 0; j2 < 8; ++j2)
                b[j2] = (n16 < 4) ? (__bf16)Wxl[(kh*32 + q*8 + j2)*4 + n16] : (__bf16)0.f;
            wxf[kh] = b;
        }

        #pragma unroll
        for (int t = 0; t < 9; ++t) {
            __bf16* mT = &mstT[t & 1][0];
            const int e  = t*16 + n16;
            const int ec = (e < NEDGE) ? e : (NEDGE - 1);
            const int i  = ec / 11;
            const int jj = ec - i * 11;
            const int j  = jj + (jj >= i);
            const f32x4 rd = *(const f32x4*)(sRad + ec * 4);
            // s1 A-frags built directly in A-layout
            bf16_8 af0, af1;
            #pragma unroll
            for (int kh = 0; kh < 2; ++kh) {
                const int cb = kh*32 + q*8;
                bf16_8 ha = *(const bf16_8*)(sHa + i*LDB + cb);
                bf16_8 hb = *(const bf16_8*)(sHb + j*LDB + cb);
                f32x4 wr0 = {0.f,0.f,0.f,0.f}, wr1 = {0.f,0.f,0.f,0.f};
                #pragma unroll
                for (int v = 0; v < 4; ++v) {
                    f32x4 wa = *(const f32x4*)(sWb + v*64 + cb);        // loop-invariant
                    f32x4 wb = *(const f32x4*)(sWb + v*64 + cb + 4);
                    wr0 += rd[v] * wa; wr1 += rd[v] * wb;
                }
                bf16_8 a;
                #pragma unroll
                for (int c = 0; c < 4; ++c)
                    a[c]   = (__bf16)silu_f((float)ha[c]   + (float)hb[c]   + wr0[c]);
                #pragma unroll
                for (int c = 0; c < 4; ++c)
                    a[4+c] = (__bf16)silu_f((float)ha[4+c] + (float)hb[4+c] + wr1[c]);
                if (kh == 0) af0 = a; else af1 = a;
            }
            // m = silu(s1@We2 + be2) -> transposed staging: mT[col*LDT + row],
            // C-frag rows q*4..q*4+3 consecutive -> one b64 per nt
            #pragma unroll
            for (int nt = 0; nt < 4; ++nt) {
                f32x4 acc = {0.f,0.f,0.f,0.f};
                acc = MFMA(af0, w2f[nt][0], acc);
                acc = MFMA(af1, w2f[nt][1], acc);
                bf16_4 mv;
                #pragma unroll
                for (int r = 0; r < 4; ++r) mv[r] = (__bf16)silu_f(acc[r] + be2q[nt]);
                *(bf16_4*)(mT + (nt*16 + n16)*LDT + q*4) = mv;
            }
            // wc = m@Wx + bx via MFMA; A-frag A[n16][q*8+j] = mT[(q*8+j)*LDT + n16]
            {
                bf16_8 aw0, aw1;
                #pragma unroll
                for (int j2 = 0; j2 < 8; ++j2) {
                    aw0[j2] = mT[(q*8 + j2)*LDT + n16];
                    aw1[j2] = mT[(32 + q*8 + j2)*LDT + n16];
                }
                f32x4 acc = {0.f,0.f,0.f,0.f};
                acc = MFMA(aw0, wxf[0], acc);
                acc = MFMA(aw1, wxf[1], acc);
                if (n16 < 4) {
                    #pragma unroll
                    for (int r = 0; r < 4; ++r) {
                        int row = t*16 + q*4 + r;
                        if (row < NEDGE) sWcB[row*4 + n16] = (__bf16)(acc[r] + bxv);
                    }
                }
            }
            // agg: lane = col; vectorized b64 reads of mT[lane*LDT + el]
            {
                bf16_4 c0 = *(const bf16_4*)(mT + lane*LDT + 0);
                #pragma unroll
                for (int el = 0; el < 4; ++el) agg[(t*16 + el)/11] += (float)c0[el];
                if (t < 8) {
                    bf16_4 c1 = *(const bf16_4*)(mT + lane*LDT + 4);
                    bf16_4 c2 = *(const bf16_4*)(mT + lane*LDT + 8);
                    bf16_4 c3 = *(const bf16_4*)(mT + lane*LDT + 12);
                    #pragma unroll
                    for (int el = 0; el < 4; ++el) {
                        agg[(t*16 + 4  + el)/11] += (float)c1[el];
                        agg[(t*16 + 8  + el)/11] += (float)c2[el];
                        agg[(t*16 + 12 + el)/11] += (float)c3[el];
                    }
                }
            }
        }
        // agg -> sHb (Hb dead after edge loop)
        #pragma unroll
        for (int i = 0; i < NAG; ++i) sHb[i*LDB + lane] = (__bf16)agg[i];

        // ---- xacc (pre-update x reads) ----
        float xn[3];
        #pragma unroll
        for (int p = 0; p < 3; ++p) {
            int idx = p*64 + lane;
            float res = 0.f;
            if (idx < 144) {
                int xi = idx / 12, dv = idx % 12, v = dv & 3;
                float xiv = sx[xi*16 + dv];
                float acc = 0.f;
                #pragma unroll
                for (int j2 = 0; j2 < NAG; ++j2) {
                    int e2 = xi*11 + j2 - (j2 > xi ? 1 : 0);
                    e2 = (e2 < NEDGE) ? e2 : (NEDGE - 1);
                    float term = (xiv - sx[j2*16 + dv]) * (float)sWcB[e2*4 + v];
                    acc += (j2 == xi) ? 0.f : term;
                }
                res = xiv + acc * (1.0f / 11.0f);
            }
            xn[p] = res;
        }
        // ---- Wh1: t1 = silu([h,agg]@Wh1 + bh1) -> sHa (reuse) ----
        {
            bf16_8 ah0 = *(const bf16_8*)(sh  + rowA*LDB + q*8);
            bf16_8 ah1 = *(const bf16_8*)(sh  + rowA*LDB + 32 + q*8);
            bf16_8 ag0 = *(const bf16_8*)(sHb + rowA*LDB + q*8);
            bf16_8 ag1 = *(const bf16_8*)(sHb + rowA*LDB + 32 + q*8);
            #pragma unroll
            for (int nt = 0; nt < 4; ++nt) {
                f32x4 acc = {0.f,0.f,0.f,0.f};
                acc = MFMA(ah0, frg<WS>(wsb, L+24+nt*4+0, Wh1l, 0,  nt*16+n16, lane), acc);
                acc = MFMA(ah1, frg<WS>(wsb, L+24+nt*4+1, Wh1l, 32, nt*16+n16, lane), acc);
                acc = MFMA(ag0, frg<WS>(wsb, L+24+nt*4+2, Wh1l, 64, nt*16+n16, lane), acc);
                acc = MFMA(ag1, frg<WS>(wsb, L+24+nt*4+3, Wh1l, 96, nt*16+n16, lane), acc);
                #pragma unroll
                for (int r = 0; r < 4; ++r) {
                    int row = q*4 + r;
                    if (row < NAG) sHa[row*LDB + nt*16+n16] = (__bf16)silu_f(acc[r] + bh1q[nt]);
                }
            }
        }
        // ---- x writeback; Wh2: h += t1@Wh2 + bh2 (register residual) ----
        #pragma unroll
        for (int p = 0; p < 3; ++p) {
            int idx = p*64 + lane;
            if (idx < 144) sx[(idx/12)*16 + idx%12] = xn[p];
        }
        {
            bf16_8 at0 = *(const bf16_8*)(sHa + rowA*LDB + q*8);
            bf16_8 at1 = *(const bf16_8*)(sHa + rowA*LDB + 32 + q*8);
            #pragma unroll
            for (int nt = 0; nt < 4; ++nt) {
                f32x4 acc = {0.f,0.f,0.f,0.f};
                acc = MFMA(at0, frg<WS>(wsb, L+40+nt*2+0, Wh2l, 0,  nt*16+n16, lane), acc);
                acc = MFMA(at1, frg<WS>(wsb, L+40+nt*2+1, Wh2l, 32, nt*16+n16, lane), acc);
                #pragma unroll
                for (int r = 0; r < 4; ++r) hC[nt][r] += acc[r] + bh2q[nt];
            }
            #pragma unroll
            for (int nt = 0; nt < 4; ++nt)
                #pragma unroll
                for (int r = 0; r < 4; ++r) {
                    int row = q*4 + r;
                    if (row < NAG) sh[row*LDB + nt*16+n16] = (__bf16)hC[nt][r];
                }
        }
    }

    // ---- epilogue: mu only (log-prob half already written) ----
    if (lane < NAG * 3) {
        int i = lane / 3, d = lane - i * 3;
        float mu = 0.f;
        #pragma unroll
        for (int v = 0; v < 4; ++v) mu += sx[i*16 + d*4 + v] * w_act[v];
        out[env * (NAG*3) + lane] = mu;
    }
}

extern "C" void kernel_launch(void* const* d_in, const int* in_sizes, int n_in,
                              void* d_out, int out_size, void* d_ws, size_t ws_size,
                              hipStream_t stream) {
    // inputs: h0,x0,W_embed,b_embed,We1,be1,We2,be2,Wx,bx,Wh1,bh1,Wh2,bh2,w_act,log_std,row,col
    const float* h0   = (const float*)d_in[0];
    const float* x0   = (const float*)d_in[1];
    const float* Wem  = (const float*)d_in[2];
    const float* bem  = (const float*)d_in[3];
    const float* We1  = (const float*)d_in[4];
    const float* be1  = (const float*)d_in[5];
    const float* We2  = (const float*)d_in[6];
    const float* be2  = (const float*)d_in[7];
    const float* Wx   = (const float*)d_in[8];
    const float* bx   = (const float*)d_in[9];
    const float* Wh1  = (const float*)d_in[10];
    const float* bh1  = (const float*)d_in[11];
    const float* Wh2  = (const float*)d_in[12];
    const float* bh2  = (const float*)d_in[13];
    const float* wact = (const float*)d_in[14];
    const float* lstd = (const float*)d_in[15];
    float* out = (float*)d_out;

    if (ws_size >= (size_t)WS_BYTES) {
        prep_frags<<<dim3(WS_FRAGS + 9), dim3(64), 0, stream>>>(
            Wem, We1, We2, Wh1, Wh2, be1, be2, bh1, bh2, bx, (__bf16*)d_ws);
        egnn9<true><<<dim3(NTH), dim3(64), 0, stream>>>(
            h0, x0, Wem, bem, We1, be1, We2, be2, Wx, bx,
            Wh1, bh1, Wh2, bh2, wact, lstd, (const __bf16*)d_ws, out);
    } else {
        egnn9<false><<<dim3(NTH), dim3(64), 0, stream>>>(
            h0, x0, Wem, bem, We1, be1, We2, be2, Wx, bx,
            Wh1, bh1, Wh2, bh2, wact, lstd, nullptr, out);
    }
}

// Round 10
// 233.089 us; speedup vs baseline: 1.5095x; 1.0281x over previous
//
#include <hip/hip_runtime.h>

#define NAG 12
#define NTH 4096
#define NEDGE 132
#define LDB 72    // bf16 node-buffer row stride: 144 B, 16B-aligned, 2-way banks (free)
#define LDT 20    // mstT col stride (bf16): 40 B -> 8B-aligned b64, low-conflict

typedef __bf16 bf16_8 __attribute__((ext_vector_type(8)));
typedef __bf16 bf16_4 __attribute__((ext_vector_type(4)));
typedef float  f32x4  __attribute__((ext_vector_type(4)));

#define MFMA(a,b,c) __builtin_amdgcn_mfma_f32_16x16x32_bf16((a),(b),(c),0,0,0)

// ws layout:
//   frag region: 100 frags x 1024 B (64 lanes x 16 B)          [0, 102400)
//     0..3         : W_embed, nt
//     L = 4 + l*48 : We1a: L+nt*2+kh | We1b: L+8+nt*2+kh | We2: L+16+nt*2+kh
//                    Wh1: L+24+nt*4+ks | Wh2: L+40+nt*2+kh
//   bias region (fp32): float idx 25600 + ((l*4+w)*64+lane)*4  [102400, 110592)
//     w: 0=be1 1=be2 2=bh1 3=bh2 ; entry = f32x4 over nt
//   bx region  (fp32): float idx 27648 + l*64 + lane           [110592, 111104)
#define WS_FRAGS 100
#define WS_BIAS_F32 25600
#define WS_BX_F32   27648
#define WS_BYTES 111104

__device__ __forceinline__ float silu_f(float z) {
    float e = __expf(-z);
    return z * __builtin_amdgcn_rcpf(1.0f + e);
}

// B-frag from fp32 row-major [K][64]: lane holds B[kbase+q*8+j][n]  (verified R2)
__device__ __forceinline__ bf16_8 loadB64(const float* __restrict__ W, int kbase, int n, int q) {
    bf16_8 b;
    #pragma unroll
    for (int j = 0; j < 8; ++j) b[j] = (__bf16)W[(kbase + q*8 + j) * 64 + n];
    return b;
}

// A-frag from 8 consecutive fp32 (16B-aligned)
__device__ __forceinline__ bf16_8 packA8(const float* S) {
    f32x4 u = *(const f32x4*)S, v = *(const f32x4*)(S + 4);
    bf16_8 a;
    a[0]=(__bf16)u.x; a[1]=(__bf16)u.y; a[2]=(__bf16)u.z; a[3]=(__bf16)u.w;
    a[4]=(__bf16)v.x; a[5]=(__bf16)v.y; a[6]=(__bf16)v.z; a[7]=(__bf16)v.w;
    return a;
}

// ---- prep: pack weight B-fragments (bf16) + bias vectors (fp32) into d_ws ----
__global__ __launch_bounds__(64) void prep_frags(
    const float* __restrict__ W_embed, const float* __restrict__ We1,
    const float* __restrict__ We2, const float* __restrict__ Wh1,
    const float* __restrict__ Wh2,
    const float* __restrict__ be1, const float* __restrict__ be2,
    const float* __restrict__ bh1, const float* __restrict__ bh2,
    const float* __restrict__ bx, __bf16* __restrict__ wsb)
{
    const int f = blockIdx.x, lane = threadIdx.x;
    const int q = lane >> 4, n16 = lane & 15;
    float* wsf = (float*)wsb;
    if (f < WS_FRAGS) {
        const float* src; int kbase, nbase;
        if (f < 4) { src = W_embed; kbase = 0; nbase = f * 16; }
        else {
            int g0 = f - 4, l = g0 / 48, r = g0 % 48;
            if      (r < 8)  { int nt=r>>1, kh=r&1;            src = We1 + l*NEDGE*64; kbase = kh*32;      nbase = nt*16; }
            else if (r < 16) { int rr=r-8,  nt=rr>>1, kh=rr&1; src = We1 + l*NEDGE*64; kbase = 64 + kh*32; nbase = nt*16; }
            else if (r < 24) { int rr=r-16, nt=rr>>1, kh=rr&1; src = We2 + l*64*64;    kbase = kh*32;      nbase = nt*16; }
            else if (r < 40) { int rr=r-24, nt=rr>>2, ks=rr&3; src = Wh1 + l*128*64;   kbase = ks*32;      nbase = nt*16; }
            else             { int rr=r-40, nt=rr>>1, kh=rr&1; src = Wh2 + l*64*64;    kbase = kh*32;      nbase = nt*16; }
        }
        bf16_8 b = loadB64(src, kbase, nbase + n16, q);
        *(bf16_8*)(wsb + (size_t)f * 512 + lane * 8) = b;
    } else if (f < WS_FRAGS + 8) {
        int f2 = f - WS_FRAGS, l = f2 >> 2, w = f2 & 3;
        const float* src = (w == 0 ? be1 : w == 1 ? be2 : w == 2 ? bh1 : bh2) + l * 64;
        f32x4 v = { src[n16], src[16 + n16], src[32 + n16], src[48 + n16] };
        *(f32x4*)(wsf + WS_BIAS_F32 + ((size_t)(l*4 + w) * 64 + lane) * 4) = v;
    } else {
        #pragma unroll
        for (int l = 0; l < 2; ++l)
            wsf[WS_BX_F32 + l*64 + lane] = (n16 < 4) ? bx[l*4 + n16] : 0.f;
    }
}

template<bool WS>
__device__ __forceinline__ bf16_8 frg(const __bf16* __restrict__ wsb, int fid,
                                      const float* __restrict__ src, int kbase, int n, int lane) {
    if (WS) return *(const bf16_8*)(wsb + (size_t)fid * 512 + lane * 8);
    else    return loadB64(src, kbase, n, (lane >> 4));
}

// ---- main: TWO ENVS PER WORKGROUP (2 independent waves), zero barriers ----
// R2..R9 all measured ~11-12% occupancy (~4 waves/CU) regardless of LDS
// (13-53 KB) or VGPR (140-196) -> evidence of a ~4-workgroup/CU cap external
// to resource arithmetic. Packing 2 fully-independent waves (one env each,
// private LDS slices, no __syncthreads) into one workgroup doubles waves/CU
// under that cap; neutral under the alternatives.
// NOTE (R3/R4/R8): occupancy-hint attributes make the allocator overshoot
// (64/84 VGPR -> HBM spill storms). Plain __launch_bounds__(128) only.
template<bool WS>
__global__ void __launch_bounds__(128) egnn10(
    const float* __restrict__ h0, const float* __restrict__ x0,
    const float* __restrict__ W_embed, const float* __restrict__ b_embed,
    const float* __restrict__ We1, const float* __restrict__ be1,
    const float* __restrict__ We2, const float* __restrict__ be2,
    const float* __restrict__ Wx, const float* __restrict__ bx,
    const float* __restrict__ Wh1, const float* __restrict__ bh1,
    const float* __restrict__ Wh2, const float* __restrict__ bh2,
    const float* __restrict__ w_act, const float* __restrict__ log_std,
    const __bf16* __restrict__ wsb, float* __restrict__ out)
{
    // per-wave slice 15264 B x 2 = 30528 B/block
    __shared__ __align__(16) __bf16 sh  [2][NAG * LDB];   // h (bf16 copy; fp32 residual in regs)
    __shared__ __align__(16) __bf16 sHa [2][NAG * LDB];   // h@We1[0:64]+be1; later t1
    __shared__ __align__(16) __bf16 sHb [2][NAG * LDB];   // h@We1[64:128]; later agg (bf16)
    __shared__ __align__(16) __bf16 mstT[2][2][64 * LDT]; // m staging, transposed, dbuf
    __shared__ __align__(16) float  sx  [2][NAG * 16];    // coords [i][d*4+v]
    __shared__ __align__(16) float  sRad[2][NEDGE * 4];
    __shared__ __align__(16) __bf16 sWcB[2][NEDGE * 4];   // coord weights (bf16)
    __shared__ __align__(16) float  sWb [2][4 * 64];      // We1 radial rows (fp32)

    const int tid  = threadIdx.x;
    const int w    = tid >> 6;          // wave slot 0/1 = env slot
    const int lane = tid & 63;
    const int q = lane >> 4, n16 = lane & 15;
    const int rowA = (n16 < NAG) ? n16 : (NAG - 1);
    const int env  = blockIdx.x * 2 + w;
    const float* wsf = (const float*)wsb;

    __bf16* shW  = sh[w];
    __bf16* sHaW = sHa[w];
    __bf16* sHbW = sHb[w];
    float*  sxW  = sx[w];
    float*  sRadW = sRad[w];
    __bf16* sWcW = sWcB[w];
    float*  sWbW = sWb[w];

    // ---- constant log-prob half of the output: off the dependence tail ----
    if (lane < NAG * 3) {
        int d = lane % 3;
        out[NTH * NAG * 3 + env * (NAG*3) + lane] = -log_std[d] - 0.9189385332046727f;
    }

    // ---- load x ----
    #pragma unroll
    for (int p = 0; p < 3; ++p) {
        int idx = p * 64 + lane;
        if (idx < NAG * 12) sxW[(idx / 12) * 16 + idx % 12] = x0[env * NAG * 12 + idx];
    }

    // ---- embed: h = h0 @ W_embed + b; residual kept in C-frag registers (fp32) ----
    f32x4 hC[4];
    {
        const float* hp = h0 + (env * NAG + rowA) * 32 + q * 8;
        bf16_8 a = packA8(hp);
        #pragma unroll
        for (int nt = 0; nt < 4; ++nt) {
            bf16_8 b = frg<WS>(wsb, nt, W_embed, 0, nt*16 + n16, lane);
            f32x4 acc = {0.f,0.f,0.f,0.f};
            acc = MFMA(a, b, acc);
            float bias = b_embed[nt*16 + n16];
            #pragma unroll
            for (int r = 0; r < 4; ++r) acc[r] += bias;
            hC[nt] = acc;
        }
        #pragma unroll
        for (int nt = 0; nt < 4; ++nt)
            #pragma unroll
            for (int r = 0; r < 4; ++r) {
                int row = q*4 + r;
                if (row < NAG) shW[row*LDB + nt*16 + n16] = (__bf16)hC[nt][r];
            }
    }

    #pragma unroll 1
    for (int l = 0; l < 2; ++l) {
        const float* We1l = We1 + l * NEDGE * 64;
        const float* be1l = be1 + l * 64;
        const float* be2l = be2 + l * 64;
        const float* Wxl  = Wx  + l * 64 * 4;
        const float* bxl  = bx  + l * 4;
        const float* We2l = We2 + l * 64 * 64;
        const float* Wh1l = Wh1 + l * 128 * 64;
        const float* bh1l = bh1 + l * 64;
        const float* Wh2l = Wh2 + l * 64 * 64;
        const float* bh2l = bh2 + l * 64;
        const int L = 4 + l * 48;

        f32x4 be1q, be2q, bh1q, bh2q;   // [nt]
        float bxv;
        if (WS) {
            const float* bb = wsf + WS_BIAS_F32 + (size_t)(l*4) * 256 + lane * 4;
            be1q = *(const f32x4*)(bb);
            be2q = *(const f32x4*)(bb + 256);
            bh1q = *(const f32x4*)(bb + 512);
            bh2q = *(const f32x4*)(bb + 768);
            bxv  = wsf[WS_BX_F32 + l*64 + lane];
        } else {
            #pragma unroll
            for (int nt = 0; nt < 4; ++nt) {
                be1q[nt] = be1l[nt*16+n16]; be2q[nt] = be2l[nt*16+n16];
                bh1q[nt] = bh1l[nt*16+n16]; bh2q[nt] = bh2l[nt*16+n16];
            }
            bxv = (n16 < 4) ? bxl[n16] : 0.f;
        }

        // ---- Stage A: Ha = h@We1a + be1, Hb = h@We1b (bf16 LDS); radial; We1c stage ----
        {
            bf16_8 a0 = *(const bf16_8*)(shW + rowA*LDB + q*8);
            bf16_8 a1 = *(const bf16_8*)(shW + rowA*LDB + 32 + q*8);
            #pragma unroll
            for (int nt = 0; nt < 4; ++nt) {
                bf16_8 b0 = frg<WS>(wsb, L+nt*2+0,   We1l, 0,  nt*16+n16, lane);
                bf16_8 b1 = frg<WS>(wsb, L+nt*2+1,   We1l, 32, nt*16+n16, lane);
                bf16_8 c0 = frg<WS>(wsb, L+8+nt*2+0, We1l, 64, nt*16+n16, lane);
                bf16_8 c1 = frg<WS>(wsb, L+8+nt*2+1, We1l, 96, nt*16+n16, lane);
                f32x4 aA = {0.f,0.f,0.f,0.f}, aB = {0.f,0.f,0.f,0.f};
                aA = MFMA(a0, b0, aA); aA = MFMA(a1, b1, aA);
                aB = MFMA(a0, c0, aB); aB = MFMA(a1, c1, aB);
                #pragma unroll
                for (int r = 0; r < 4; ++r) {
                    int row = q*4 + r;
                    if (row < NAG) {
                        sHaW[row*LDB + nt*16+n16] = (__bf16)(aA[r] + be1q[nt]);
                        sHbW[row*LDB + nt*16+n16] = (__bf16)aB[r];
                    }
                }
            }
        }
        #pragma unroll
        for (int p = 0; p < 4; ++p) sWbW[p*64 + lane] = We1l[(128+p)*64 + lane];
        #pragma unroll
        for (int p = 0; p < 9; ++p) {
            int idx = p * 64 + lane;
            if (idx < NEDGE * 4) {
                int e = idx >> 2, v = idx & 3;
                int i = e / 11, jj = e - i * 11, j = jj + (jj >= i);
                float r = 0.f;
                #pragma unroll
                for (int d = 0; d < 3; ++d) {
                    float df = sxW[i*16 + d*4 + v] - sxW[j*16 + d*4 + v];
                    r += df * df;
                }
                sRadW[idx] = r;
            }
        }

        // ---- Edge stage: 9 M-tiles; transposed + double-buffered m staging ----
        float agg[NAG];
        #pragma unroll
        for (int i = 0; i < NAG; ++i) agg[i] = 0.f;
        bf16_8 w2f[4][2], wxf[2];
        #pragma unroll
        for (int nt = 0; nt < 4; ++nt) {
            w2f[nt][0] = frg<WS>(wsb, L+16+nt*2+0, We2l, 0,  nt*16+n16, lane);
            w2f[nt][1] = frg<WS>(wsb, L+16+nt*2+1, We2l, 32, nt*16+n16, lane);
        }
        #pragma unroll
        for (int kh = 0; kh < 2; ++kh) {   // Wx B-frag, cols 4..15 zero-padded
            bf16_8 b;
            #pragma unroll
            for (int j2 = 0; j2 < 8; ++j2)
                b[j2] = (n16 < 4) ? (__bf16)Wxl[(kh*32 + q*8 + j2)*4 + n16] : (__bf16)0.f;
            wxf[kh] = b;
        }

        #pragma unroll
        for (int t = 0; t < 9; ++t) {
            __bf16* mT = &mstT[w][t & 1][0];
            const int e  = t*16 + n16;
            const int ec = (e < NEDGE) ? e : (NEDGE - 1);
            const int i  = ec / 11;
            const int jj = ec - i * 11;
            const int j  = jj + (jj >= i);
            const f32x4 rd = *(const f32x4*)(sRadW + ec * 4);
            // s1 A-frags built directly in A-layout
            bf16_8 af0, af1;
            #pragma unroll
            for (int kh = 0; kh < 2; ++kh) {
                const int cb = kh*32 + q*8;
                bf16_8 ha = *(const bf16_8*)(sHaW + i*LDB + cb);
                bf16_8 hb = *(const bf16_8*)(sHbW + j*LDB + cb);
                f32x4 wr0 = {0.f,0.f,0.f,0.f}, wr1 = {0.f,0.f,0.f,0.f};
                #pragma unroll
                for (int v = 0; v < 4; ++v) {
                    f32x4 wa = *(const f32x4*)(sWbW + v*64 + cb);       // loop-invariant
                    f32x4 wb = *(const f32x4*)(sWbW + v*64 + cb + 4);
                    wr0 += rd[v] * wa; wr1 += rd[v] * wb;
                }
                bf16_8 a;
                #pragma unroll
                for (int c = 0; c < 4; ++c)
                    a[c]   = (__bf16)silu_f((float)ha[c]   + (float)hb[c]   + wr0[c]);
                #pragma unroll
                for (int c = 0; c < 4; ++c)
                    a[4+c] = (__bf16)silu_f((float)ha[4+c] + (float)hb[4+c] + wr1[c]);
                if (kh == 0) af0 = a; else af1 = a;
            }
            // m = silu(s1@We2 + be2) -> transposed staging: mT[col*LDT + row]
            #pragma unroll
            for (int nt = 0; nt < 4; ++nt) {
                f32x4 acc = {0.f,0.f,0.f,0.f};
                acc = MFMA(af0, w2f[nt][0], acc);
                acc = MFMA(af1, w2f[nt][1], acc);
                bf16_4 mv;
                #pragma unroll
                for (int r = 0; r < 4; ++r) mv[r] = (__bf16)silu_f(acc[r] + be2q[nt]);
                *(bf16_4*)(mT + (nt*16 + n16)*LDT + q*4) = mv;
            }
            // wc = m@Wx + bx via MFMA; A-frag A[n16][q*8+j] = mT[(q*8+j)*LDT + n16]
            {
                bf16_8 aw0, aw1;
                #pragma unroll
                for (int j2 = 0; j2 < 8; ++j2) {
                    aw0[j2] = mT[(q*8 + j2)*LDT + n16];
                    aw1[j2] = mT[(32 + q*8 + j2)*LDT + n16];
                }
                f32x4 acc = {0.f,0.f,0.f,0.f};
                acc = MFMA(aw0, wxf[0], acc);
                acc = MFMA(aw1, wxf[1], acc);
                if (n16 < 4) {
                    #pragma unroll
                    for (int r = 0; r < 4; ++r) {
                        int row = t*16 + q*4 + r;
                        if (row < NEDGE) sWcW[row*4 + n16] = (__bf16)(acc[r] + bxv);
                    }
                }
            }
            // agg: lane = col; vectorized b64 reads of mT[lane*LDT + el]
            {
                bf16_4 c0 = *(const bf16_4*)(mT + lane*LDT + 0);
                #pragma unroll
                for (int el = 0; el < 4; ++el) agg[(t*16 + el)/11] += (float)c0[el];
                if (t < 8) {
                    bf16_4 c1 = *(const bf16_4*)(mT + lane*LDT + 4);
                    bf16_4 c2 = *(const bf16_4*)(mT + lane*LDT + 8);
                    bf16_4 c3 = *(const bf16_4*)(mT + lane*LDT + 12);
                    #pragma unroll
                    for (int el = 0; el < 4; ++el) {
                        agg[(t*16 + 4  + el)/11] += (float)c1[el];
                        agg[(t*16 + 8  + el)/11] += (float)c2[el];
                        agg[(t*16 + 12 + el)/11] += (float)c3[el];
                    }
                }
            }
        }
        // agg -> sHb (Hb dead after edge loop)
        #pragma unroll
        for (int i = 0; i < NAG; ++i) sHbW[i*LDB + lane] = (__bf16)agg[i];

        // ---- xacc (pre-update x reads) ----
        float xn[3];
        #pragma unroll
        for (int p = 0; p < 3; ++p) {
            int idx = p*64 + lane;
            float res = 0.f;
            if (idx < 144) {
                int xi = idx / 12, dv = idx % 12, v = dv & 3;
                float xiv = sxW[xi*16 + dv];
                float acc = 0.f;
                #pragma unroll
                for (int j2 = 0; j2 < NAG; ++j2) {
                    int e2 = xi*11 + j2 - (j2 > xi ? 1 : 0);
                    e2 = (e2 < NEDGE) ? e2 : (NEDGE - 1);
                    float term = (xiv - sxW[j2*16 + dv]) * (float)sWcW[e2*4 + v];
                    acc += (j2 == xi) ? 0.f : term;
                }
                res = xiv + acc * (1.0f / 11.0f);
            }
            xn[p] = res;
        }
        // ---- Wh1: t1 = silu([h,agg]@Wh1 + bh1) -> sHa (reuse) ----
        {
            bf16_8 ah0 = *(const bf16_8*)(shW  + rowA*LDB + q*8);
            bf16_8 ah1 = *(const bf16_8*)(shW  + rowA*LDB + 32 + q*8);
            bf16_8 ag0 = *(const bf16_8*)(sHbW + rowA*LDB + q*8);
            bf16_8 ag1 = *(const bf16_8*)(sHbW + rowA*LDB + 32 + q*8);
            #pragma unroll
            for (int nt = 0; nt < 4; ++nt) {
                f32x4 acc = {0.f,0.f,0.f,0.f};
                acc = MFMA(ah0, frg<WS>(wsb, L+24+nt*4+0, Wh1l, 0,  nt*16+n16, lane), acc);
                acc = MFMA(ah1, frg<WS>(wsb, L+24+nt*4+1, Wh1l, 32, nt*16+n16, lane), acc);
                acc = MFMA(ag0, frg<WS>(wsb, L+24+nt*4+2, Wh1l, 64, nt*16+n16, lane), acc);
                acc = MFMA(ag1, frg<WS>(wsb, L+24+nt*4+3, Wh1l, 96, nt*16+n16, lane), acc);
                #pragma unroll
                for (int r = 0; r < 4; ++r) {
                    int row = q*4 + r;
                    if (row < NAG) sHaW[row*LDB + nt*16+n16] = (__bf16)silu_f(acc[r] + bh1q[nt]);
                }
            }
        }
        // ---- x writeback; Wh2: h += t1@Wh2 + bh2 (register residual) ----
        #pragma unroll
        for (int p = 0; p < 3; ++p) {
            int idx = p*64 + lane;
            if (idx < 144) sxW[(idx/12)*16 + idx%12] = xn[p];
        }
        {
            bf16_8 at0 = *(const bf16_8*)(sHaW + rowA*LDB + q*8);
            bf16_8 at1 = *(const bf16_8*)(sHaW + rowA*LDB + 32 + q*8);
            #pragma unroll
            for (int nt = 0; nt < 4; ++nt) {
                f32x4 acc = {0.f,0.f,0.f,0.f};
                acc = MFMA(at0, frg<WS>(wsb, L+40+nt*2+0, Wh2l, 0,  nt*16+n16, lane), acc);
                acc = MFMA(at1, frg<WS>(wsb, L+40+nt*2+1, Wh2l, 32, nt*16+n16, lane), acc);
                #pragma unroll
                for (int r = 0; r < 4; ++r) hC[nt][r] += acc[r] + bh2q[nt];
            }
            #pragma unroll
            for (int nt = 0; nt < 4; ++nt)
                #pragma unroll
                for (int r = 0; r < 4; ++r) {
                    int row = q*4 + r;
                    if (row < NAG) shW[row*LDB + nt*16+n16] = (__bf16)hC[nt][r];
                }
        }
    }

    // ---- epilogue: mu only (log-prob half already written) ----
    if (lane < NAG * 3) {
        int i = lane / 3, d = lane - i * 3;
        float mu = 0.f;
        #pragma unroll
        for (int v = 0; v < 4; ++v) mu += sxW[i*16 + d*4 + v] * w_act[v];
        out[env * (NAG*3) + lane] = mu;
    }
}

extern "C" void kernel_launch(void* const* d_in, const int* in_sizes, int n_in,
                              void* d_out, int out_size, void* d_ws, size_t ws_size,
                              hipStream_t stream) {
    // inputs: h0,x0,W_embed,b_embed,We1,be1,We2,be2,Wx,bx,Wh1,bh1,Wh2,bh2,w_act,log_std,row,col
    const float* h0   = (const float*)d_in[0];
    const float* x0   = (const float*)d_in[1];
    const float* Wem  = (const float*)d_in[2];
    const float* bem  = (const float*)d_in[3];
    const float* We1  = (const float*)d_in[4];
    const float* be1  = (const float*)d_in[5];
    const float* We2  = (const float*)d_in[6];
    const float* be2  = (const float*)d_in[7];
    const float* Wx   = (const float*)d_in[8];
    const float* bx   = (const float*)d_in[9];
    const float* Wh1  = (const float*)d_in[10];
    const float* bh1  = (const float*)d_in[11];
    const float* Wh2  = (const float*)d_in[12];
    const float* bh2  = (const float*)d_in[13];
    const float* wact = (const float*)d_in[14];
    const float* lstd = (const float*)d_in[15];
    float* out = (float*)d_out;

    if (ws_size >= (size_t)WS_BYTES) {
        prep_frags<<<dim3(WS_FRAGS + 9), dim3(64), 0, stream>>>(
            Wem, We1, We2, Wh1, Wh2, be1, be2, bh1, bh2, bx, (__bf16*)d_ws);
        egnn10<true><<<dim3(NTH / 2), dim3(128), 0, stream>>>(
            h0, x0, Wem, bem, We1, be1, We2, be2, Wx, bx,
            Wh1, bh1, Wh2, bh2, wact, lstd, (const __bf16*)d_ws, out);
    } else {
        egnn10<false><<<dim3(NTH / 2), dim3(128), 0, stream>>>(
            h0, x0, Wem, bem, We1, be1, We2, be2, Wx, bx,
            Wh1, bh1, Wh2, bh2, wact, lstd, nullptr, out);
    }
}

// Round 11
// 225.695 us; speedup vs baseline: 1.5589x; 1.0328x over previous
//
#include <hip/hip_runtime.h>

#define NAG 12
#define NTH 4096
#define NEDGE 132
#define LDB 72    // bf16 node-buffer row stride: 144 B, 16B-aligned, 2-way banks (free)
#define LDT 20    // mstT col stride (bf16): 40 B -> 8B-aligned b64, low-conflict

typedef __bf16 bf16_8 __attribute__((ext_vector_type(8)));
typedef __bf16 bf16_4 __attribute__((ext_vector_type(4)));
typedef float  f32x4  __attribute__((ext_vector_type(4)));

#define MFMA(a,b,c) __builtin_amdgcn_mfma_f32_16x16x32_bf16((a),(b),(c),0,0,0)

// ws layout:
//   frag region: 100 frags x 1024 B (64 lanes x 16 B)          [0, 102400)
//     0..3         : W_embed, nt
//     L = 4 + l*48 : We1a: L+nt*2+kh | We1b: L+8+nt*2+kh | We2: L+16+nt*2+kh
//                    Wh1: L+24+nt*4+ks | Wh2: L+40+nt*2+kh
//   bias region (fp32): float idx 25600 + ((l*4+w)*64+lane)*4  [102400, 110592)
//   bx region  (fp32): float idx 27648 + l*64 + lane           [110592, 111104)
#define WS_FRAGS 100
#define WS_BIAS_F32 25600
#define WS_BX_F32   27648
#define WS_BYTES 111104

__device__ __forceinline__ float silu_f(float z) {
    float e = __expf(-z);
    return z * __builtin_amdgcn_rcpf(1.0f + e);
}

// B-frag from fp32 row-major [K][64]: lane holds B[kbase+q*8+j][n]  (verified R2)
__device__ __forceinline__ bf16_8 loadB64(const float* __restrict__ W, int kbase, int n, int q) {
    bf16_8 b;
    #pragma unroll
    for (int j = 0; j < 8; ++j) b[j] = (__bf16)W[(kbase + q*8 + j) * 64 + n];
    return b;
}

// A-frag from 8 consecutive fp32 (16B-aligned)
__device__ __forceinline__ bf16_8 packA8(const float* S) {
    f32x4 u = *(const f32x4*)S, v = *(const f32x4*)(S + 4);
    bf16_8 a;
    a[0]=(__bf16)u.x; a[1]=(__bf16)u.y; a[2]=(__bf16)u.z; a[3]=(__bf16)u.w;
    a[4]=(__bf16)v.x; a[5]=(__bf16)v.y; a[6]=(__bf16)v.z; a[7]=(__bf16)v.w;
    return a;
}

// ---- prep: pack weight B-fragments (bf16) + bias vectors (fp32) into d_ws ----
__global__ __launch_bounds__(64) void prep_frags(
    const float* __restrict__ W_embed, const float* __restrict__ We1,
    const float* __restrict__ We2, const float* __restrict__ Wh1,
    const float* __restrict__ Wh2,
    const float* __restrict__ be1, const float* __restrict__ be2,
    const float* __restrict__ bh1, const float* __restrict__ bh2,
    const float* __restrict__ bx, __bf16* __restrict__ wsb)
{
    const int f = blockIdx.x, lane = threadIdx.x;
    const int q = lane >> 4, n16 = lane & 15;
    float* wsf = (float*)wsb;
    if (f < WS_FRAGS) {
        const float* src; int kbase, nbase;
        if (f < 4) { src = W_embed; kbase = 0; nbase = f * 16; }
        else {
            int g0 = f - 4, l = g0 / 48, r = g0 % 48;
            if      (r < 8)  { int nt=r>>1, kh=r&1;            src = We1 + l*NEDGE*64; kbase = kh*32;      nbase = nt*16; }
            else if (r < 16) { int rr=r-8,  nt=rr>>1, kh=rr&1; src = We1 + l*NEDGE*64; kbase = 64 + kh*32; nbase = nt*16; }
            else if (r < 24) { int rr=r-16, nt=rr>>1, kh=rr&1; src = We2 + l*64*64;    kbase = kh*32;      nbase = nt*16; }
            else if (r < 40) { int rr=r-24, nt=rr>>2, ks=rr&3; src = Wh1 + l*128*64;   kbase = ks*32;      nbase = nt*16; }
            else             { int rr=r-40, nt=rr>>1, kh=rr&1; src = Wh2 + l*64*64;    kbase = kh*32;      nbase = nt*16; }
        }
        bf16_8 b = loadB64(src, kbase, nbase + n16, q);
        *(bf16_8*)(wsb + (size_t)f * 512 + lane * 8) = b;
    } else if (f < WS_FRAGS + 8) {
        int f2 = f - WS_FRAGS, l = f2 >> 2, w = f2 & 3;
        const float* src = (w == 0 ? be1 : w == 1 ? be2 : w == 2 ? bh1 : bh2) + l * 64;
        f32x4 v = { src[n16], src[16 + n16], src[32 + n16], src[48 + n16] };
        *(f32x4*)(wsf + WS_BIAS_F32 + ((size_t)(l*4 + w) * 64 + lane) * 4) = v;
    } else {
        #pragma unroll
        for (int l = 0; l < 2; ++l)
            wsf[WS_BX_F32 + l*64 + lane] = (n16 < 4) ? bx[l*4 + n16] : 0.f;
    }
}

template<bool WS>
__device__ __forceinline__ bf16_8 frg(const __bf16* __restrict__ wsb, int fid,
                                      const float* __restrict__ src, int kbase, int n, int lane) {
    if (WS) return *(const bf16_8*)(wsb + (size_t)fid * 512 + lane * 8);
    else    return loadB64(src, kbase, n, (lane >> 4));
}

// ---- main: TWO ENVS PER WAVE, interleaved (ILP), zero barriers ----
// R10 falsified the workgroup-cap theory: effective residency tracks WAVES
// (~4/CU) regardless of packing/LDS/VGPR. So raise per-wave ILP instead:
// two independent env chains share one instruction stream; weight frags,
// biases and all edge-index math are env-independent -> computed once.
// NOTE (R3/R4/R8): occupancy-hint attributes cause allocator overshoot ->
// spill storms. Plain __launch_bounds__(64). FETCH_SIZE is the spill tripwire.
template<bool WS>
__global__ void __launch_bounds__(64) egnn11(
    const float* __restrict__ h0, const float* __restrict__ x0,
    const float* __restrict__ W_embed, const float* __restrict__ b_embed,
    const float* __restrict__ We1, const float* __restrict__ be1,
    const float* __restrict__ We2, const float* __restrict__ be2,
    const float* __restrict__ Wx, const float* __restrict__ bx,
    const float* __restrict__ Wh1, const float* __restrict__ bh1,
    const float* __restrict__ Wh2, const float* __restrict__ bh2,
    const float* __restrict__ w_act, const float* __restrict__ log_std,
    const __bf16* __restrict__ wsb, float* __restrict__ out)
{
    // 29504 B total
    __shared__ __align__(16) __bf16 sh  [2][NAG * LDB];
    __shared__ __align__(16) __bf16 sHa [2][NAG * LDB];
    __shared__ __align__(16) __bf16 sHb [2][NAG * LDB];
    __shared__ __align__(16) __bf16 mstT[2][2][64 * LDT];  // [env][dbuf]
    __shared__ __align__(16) float  sx  [2][NAG * 16];
    __shared__ __align__(16) float  sRad[2][NEDGE * 4];
    __shared__ __align__(16) __bf16 sWcB[2][NEDGE * 4];
    __shared__ __align__(16) float  sWb [4 * 64];          // shared (layer weights)

    const int lane = threadIdx.x;
    const int q = lane >> 4, n16 = lane & 15;
    const int rowA = (n16 < NAG) ? n16 : (NAG - 1);
    const int env0 = blockIdx.x * 2;
    const float* wsf = (const float*)wsb;

    // ---- constant log-prob half of the output ----
    if (lane < NAG * 3) {
        int d = lane % 3;
        float lp = -log_std[d] - 0.9189385332046727f;
        out[NTH * NAG * 3 + (env0 + 0) * (NAG*3) + lane] = lp;
        out[NTH * NAG * 3 + (env0 + 1) * (NAG*3) + lane] = lp;
    }

    // ---- load x (both envs: 288 floats contiguous) ----
    #pragma unroll
    for (int p = 0; p < 5; ++p) {
        int idx = p * 64 + lane;
        if (idx < 2 * NAG * 12) {
            int ep = idx / 144, r2 = idx - ep * 144;
            sx[ep][(r2 / 12) * 16 + r2 % 12] = x0[(env0) * NAG * 12 + idx];
        }
    }

    // ---- embed: h = h0 @ W_embed + b (shared B-frags) ----
    f32x4 hC[2][4];
    {
        bf16_8 a[2];
        #pragma unroll
        for (int ep = 0; ep < 2; ++ep)
            a[ep] = packA8(h0 + ((env0 + ep) * NAG + rowA) * 32 + q * 8);
        #pragma unroll
        for (int nt = 0; nt < 4; ++nt) {
            bf16_8 b = frg<WS>(wsb, nt, W_embed, 0, nt*16 + n16, lane);
            float bias = b_embed[nt*16 + n16];
            #pragma unroll
            for (int ep = 0; ep < 2; ++ep) {
                f32x4 acc = {0.f,0.f,0.f,0.f};
                acc = MFMA(a[ep], b, acc);
                #pragma unroll
                for (int r = 0; r < 4; ++r) acc[r] += bias;
                hC[ep][nt] = acc;
            }
        }
        #pragma unroll
        for (int ep = 0; ep < 2; ++ep)
            #pragma unroll
            for (int nt = 0; nt < 4; ++nt)
                #pragma unroll
                for (int r = 0; r < 4; ++r) {
                    int row = q*4 + r;
                    if (row < NAG) sh[ep][row*LDB + nt*16 + n16] = (__bf16)hC[ep][nt][r];
                }
    }

    #pragma unroll 1
    for (int l = 0; l < 2; ++l) {
        const float* We1l = We1 + l * NEDGE * 64;
        const float* be1l = be1 + l * 64;
        const float* be2l = be2 + l * 64;
        const float* Wxl  = Wx  + l * 64 * 4;
        const float* bxl  = bx  + l * 4;
        const float* We2l = We2 + l * 64 * 64;
        const float* Wh1l = Wh1 + l * 128 * 64;
        const float* bh1l = bh1 + l * 64;
        const float* Wh2l = Wh2 + l * 64 * 64;
        const float* bh2l = bh2 + l * 64;
        const int L = 4 + l * 48;

        f32x4 be1q, be2q, bh1q, bh2q;
        float bxv;
        if (WS) {
            const float* bb = wsf + WS_BIAS_F32 + (size_t)(l*4) * 256 + lane * 4;
            be1q = *(const f32x4*)(bb);
            be2q = *(const f32x4*)(bb + 256);
            bh1q = *(const f32x4*)(bb + 512);
            bh2q = *(const f32x4*)(bb + 768);
            bxv  = wsf[WS_BX_F32 + l*64 + lane];
        } else {
            #pragma unroll
            for (int nt = 0; nt < 4; ++nt) {
                be1q[nt] = be1l[nt*16+n16]; be2q[nt] = be2l[nt*16+n16];
                bh1q[nt] = bh1l[nt*16+n16]; bh2q[nt] = bh2l[nt*16+n16];
            }
            bxv = (n16 < 4) ? bxl[n16] : 0.f;
        }

        // ---- Stage A: Ha/Hb (shared B-frags, 2 env A-frags); radial; We1c ----
        {
            bf16_8 a0[2], a1[2];
            #pragma unroll
            for (int ep = 0; ep < 2; ++ep) {
                a0[ep] = *(const bf16_8*)(sh[ep] + rowA*LDB + q*8);
                a1[ep] = *(const bf16_8*)(sh[ep] + rowA*LDB + 32 + q*8);
            }
            #pragma unroll
            for (int nt = 0; nt < 4; ++nt) {
                bf16_8 b0 = frg<WS>(wsb, L+nt*2+0,   We1l, 0,  nt*16+n16, lane);
                bf16_8 b1 = frg<WS>(wsb, L+nt*2+1,   We1l, 32, nt*16+n16, lane);
                bf16_8 c0 = frg<WS>(wsb, L+8+nt*2+0, We1l, 64, nt*16+n16, lane);
                bf16_8 c1 = frg<WS>(wsb, L+8+nt*2+1, We1l, 96, nt*16+n16, lane);
                #pragma unroll
                for (int ep = 0; ep < 2; ++ep) {
                    f32x4 aA = {0.f,0.f,0.f,0.f}, aB = {0.f,0.f,0.f,0.f};
                    aA = MFMA(a0[ep], b0, aA); aA = MFMA(a1[ep], b1, aA);
                    aB = MFMA(a0[ep], c0, aB); aB = MFMA(a1[ep], c1, aB);
                    #pragma unroll
                    for (int r = 0; r < 4; ++r) {
                        int row = q*4 + r;
                        if (row < NAG) {
                            sHa[ep][row*LDB + nt*16+n16] = (__bf16)(aA[r] + be1q[nt]);
                            sHb[ep][row*LDB + nt*16+n16] = (__bf16)aB[r];
                        }
                    }
                }
            }
        }
        #pragma unroll
        for (int p = 0; p < 4; ++p) sWb[p*64 + lane] = We1l[(128+p)*64 + lane];
        #pragma unroll
        for (int p = 0; p < 9; ++p) {
            int idx = p * 64 + lane;
            if (idx < NEDGE * 4) {
                int e = idx >> 2, v = idx & 3;
                int i = e / 11, jj = e - i * 11, j = jj + (jj >= i);
                #pragma unroll
                for (int ep = 0; ep < 2; ++ep) {
                    float r = 0.f;
                    #pragma unroll
                    for (int d = 0; d < 3; ++d) {
                        float df = sx[ep][i*16 + d*4 + v] - sx[ep][j*16 + d*4 + v];
                        r += df * df;
                    }
                    sRad[ep][idx] = r;
                }
            }
        }

        // ---- Edge stage: 9 M-tiles x 2 envs interleaved ----
        float agg[2][NAG];
        #pragma unroll
        for (int ep = 0; ep < 2; ++ep)
            #pragma unroll
            for (int i = 0; i < NAG; ++i) agg[ep][i] = 0.f;
        bf16_8 w2f[4][2], wxf[2];
        #pragma unroll
        for (int nt = 0; nt < 4; ++nt) {
            w2f[nt][0] = frg<WS>(wsb, L+16+nt*2+0, We2l, 0,  nt*16+n16, lane);
            w2f[nt][1] = frg<WS>(wsb, L+16+nt*2+1, We2l, 32, nt*16+n16, lane);
        }
        #pragma unroll
        for (int kh = 0; kh < 2; ++kh) {
            bf16_8 b;
            #pragma unroll
            for (int j2 = 0; j2 < 8; ++j2)
                b[j2] = (n16 < 4) ? (__bf16)Wxl[(kh*32 + q*8 + j2)*4 + n16] : (__bf16)0.f;
            wxf[kh] = b;
        }

        #pragma unroll
        for (int t = 0; t < 9; ++t) {
            // env-independent index math (amortized over both envs)
            const int e  = t*16 + n16;
            const int ec = (e < NEDGE) ? e : (NEDGE - 1);
            const int i  = ec / 11;
            const int jj = ec - i * 11;
            const int j  = jj + (jj >= i);
            // A-frags for both envs
            bf16_8 af[2][2];
            #pragma unroll
            for (int ep = 0; ep < 2; ++ep) {
                const f32x4 rd = *(const f32x4*)(sRad[ep] + ec * 4);
                #pragma unroll
                for (int kh = 0; kh < 2; ++kh) {
                    const int cb = kh*32 + q*8;
                    bf16_8 ha = *(const bf16_8*)(sHa[ep] + i*LDB + cb);
                    bf16_8 hb = *(const bf16_8*)(sHb[ep] + j*LDB + cb);
                    f32x4 wr0 = {0.f,0.f,0.f,0.f}, wr1 = {0.f,0.f,0.f,0.f};
                    #pragma unroll
                    for (int v = 0; v < 4; ++v) {
                        f32x4 wa = *(const f32x4*)(sWb + v*64 + cb);
                        f32x4 wb = *(const f32x4*)(sWb + v*64 + cb + 4);
                        wr0 += rd[v] * wa; wr1 += rd[v] * wb;
                    }
                    bf16_8 a;
                    #pragma unroll
                    for (int c = 0; c < 4; ++c)
                        a[c]   = (__bf16)silu_f((float)ha[c]   + (float)hb[c]   + wr0[c]);
                    #pragma unroll
                    for (int c = 0; c < 4; ++c)
                        a[4+c] = (__bf16)silu_f((float)ha[4+c] + (float)hb[4+c] + wr1[c]);
                    af[ep][kh] = a;
                }
            }
            // m = silu(s1@We2 + be2) -> per-env transposed staging
            #pragma unroll
            for (int ep = 0; ep < 2; ++ep) {
                __bf16* mT = &mstT[ep][t & 1][0];
                #pragma unroll
                for (int nt = 0; nt < 4; ++nt) {
                    f32x4 acc = {0.f,0.f,0.f,0.f};
                    acc = MFMA(af[ep][0], w2f[nt][0], acc);
                    acc = MFMA(af[ep][1], w2f[nt][1], acc);
                    bf16_4 mv;
                    #pragma unroll
                    for (int r = 0; r < 4; ++r) mv[r] = (__bf16)silu_f(acc[r] + be2q[nt]);
                    *(bf16_4*)(mT + (nt*16 + n16)*LDT + q*4) = mv;
                }
            }
            // wc = m@Wx + bx via MFMA (per env)
            #pragma unroll
            for (int ep = 0; ep < 2; ++ep) {
                const __bf16* mT = &mstT[ep][t & 1][0];
                bf16_8 aw0, aw1;
                #pragma unroll
                for (int j2 = 0; j2 < 8; ++j2) {
                    aw0[j2] = mT[(q*8 + j2)*LDT + n16];
                    aw1[j2] = mT[(32 + q*8 + j2)*LDT + n16];
                }
                f32x4 acc = {0.f,0.f,0.f,0.f};
                acc = MFMA(aw0, wxf[0], acc);
                acc = MFMA(aw1, wxf[1], acc);
                if (n16 < 4) {
                    #pragma unroll
                    for (int r = 0; r < 4; ++r) {
                        int row = t*16 + q*4 + r;
                        if (row < NEDGE) sWcB[ep][row*4 + n16] = (__bf16)(acc[r] + bxv);
                    }
                }
            }
            // agg: lane = col; vectorized b64 reads
            #pragma unroll
            for (int ep = 0; ep < 2; ++ep) {
                const __bf16* mT = &mstT[ep][t & 1][0];
                bf16_4 c0 = *(const bf16_4*)(mT + lane*LDT + 0);
                #pragma unroll
                for (int el = 0; el < 4; ++el) agg[ep][(t*16 + el)/11] += (float)c0[el];
                if (t < 8) {
                    bf16_4 c1 = *(const bf16_4*)(mT + lane*LDT + 4);
                    bf16_4 c2 = *(const bf16_4*)(mT + lane*LDT + 8);
                    bf16_4 c3 = *(const bf16_4*)(mT + lane*LDT + 12);
                    #pragma unroll
                    for (int el = 0; el < 4; ++el) {
                        agg[ep][(t*16 + 4  + el)/11] += (float)c1[el];
                        agg[ep][(t*16 + 8  + el)/11] += (float)c2[el];
                        agg[ep][(t*16 + 12 + el)/11] += (float)c3[el];
                    }
                }
            }
        }
        // agg -> sHb (Hb dead after edge loop)
        #pragma unroll
        for (int ep = 0; ep < 2; ++ep)
            #pragma unroll
            for (int i = 0; i < NAG; ++i) sHb[ep][i*LDB + lane] = (__bf16)agg[ep][i];

        // ---- xacc (pre-update x reads) ----
        float xn[2][3];
        #pragma unroll
        for (int p = 0; p < 3; ++p) {
            int idx = p*64 + lane;
            int xi = idx / 12, dv = idx % 12, v = dv & 3;
            bool act = idx < 144;
            int xic = act ? xi : 0;
            #pragma unroll
            for (int ep = 0; ep < 2; ++ep) {
                float xiv = sx[ep][xic*16 + dv];
                float acc = 0.f;
                #pragma unroll
                for (int j2 = 0; j2 < NAG; ++j2) {
                    int e2 = xic*11 + j2 - (j2 > xic ? 1 : 0);
                    e2 = (e2 < NEDGE) ? e2 : (NEDGE - 1);
                    float term = (xiv - sx[ep][j2*16 + dv]) * (float)sWcB[ep][e2*4 + v];
                    acc += (j2 == xic) ? 0.f : term;
                }
                xn[ep][p] = act ? (xiv + acc * (1.0f / 11.0f)) : 0.f;
            }
        }
        // ---- Wh1: t1 = silu([h,agg]@Wh1 + bh1) -> sHa ----
        {
            bf16_8 ah0[2], ah1[2], ag0[2], ag1[2];
            #pragma unroll
            for (int ep = 0; ep < 2; ++ep) {
                ah0[ep] = *(const bf16_8*)(sh[ep]  + rowA*LDB + q*8);
                ah1[ep] = *(const bf16_8*)(sh[ep]  + rowA*LDB + 32 + q*8);
                ag0[ep] = *(const bf16_8*)(sHb[ep] + rowA*LDB + q*8);
                ag1[ep] = *(const bf16_8*)(sHb[ep] + rowA*LDB + 32 + q*8);
            }
            #pragma unroll
            for (int nt = 0; nt < 4; ++nt) {
                bf16_8 b0 = frg<WS>(wsb, L+24+nt*4+0, Wh1l, 0,  nt*16+n16, lane);
                bf16_8 b1 = frg<WS>(wsb, L+24+nt*4+1, Wh1l, 32, nt*16+n16, lane);
                bf16_8 b2 = frg<WS>(wsb, L+24+nt*4+2, Wh1l, 64, nt*16+n16, lane);
                bf16_8 b3 = frg<WS>(wsb, L+24+nt*4+3, Wh1l, 96, nt*16+n16, lane);
                #pragma unroll
                for (int ep = 0; ep < 2; ++ep) {
                    f32x4 acc = {0.f,0.f,0.f,0.f};
                    acc = MFMA(ah0[ep], b0, acc); acc = MFMA(ah1[ep], b1, acc);
                    acc = MFMA(ag0[ep], b2, acc); acc = MFMA(ag1[ep], b3, acc);
                    #pragma unroll
                    for (int r = 0; r < 4; ++r) {
                        int row = q*4 + r;
                        if (row < NAG) sHa[ep][row*LDB + nt*16+n16] = (__bf16)silu_f(acc[r] + bh1q[nt]);
                    }
                }
            }
        }
        // ---- x writeback; Wh2: h += t1@Wh2 + bh2 ----
        #pragma unroll
        for (int p = 0; p < 3; ++p) {
            int idx = p*64 + lane;
            if (idx < 144) {
                #pragma unroll
                for (int ep = 0; ep < 2; ++ep)
                    sx[ep][(idx/12)*16 + idx%12] = xn[ep][p];
            }
        }
        {
            bf16_8 at0[2], at1[2];
            #pragma unroll
            for (int ep = 0; ep < 2; ++ep) {
                at0[ep] = *(const bf16_8*)(sHa[ep] + rowA*LDB + q*8);
                at1[ep] = *(const bf16_8*)(sHa[ep] + rowA*LDB + 32 + q*8);
            }
            #pragma unroll
            for (int nt = 0; nt < 4; ++nt) {
                bf16_8 b0 = frg<WS>(wsb, L+40+nt*2+0, Wh2l, 0,  nt*16+n16, lane);
                bf16_8 b1 = frg<WS>(wsb, L+40+nt*2+1, Wh2l, 32, nt*16+n16, lane);
                #pragma unroll
                for (int ep = 0; ep < 2; ++ep) {
                    f32x4 acc = {0.f,0.f,0.f,0.f};
                    acc = MFMA(at0[ep], b0, acc);
                    acc = MFMA(at1[ep], b1, acc);
                    #pragma unroll
                    for (int r = 0; r < 4; ++r) hC[ep][nt][r] += acc[r] + bh2q[nt];
                }
            }
            #pragma unroll
            for (int ep = 0; ep < 2; ++ep)
                #pragma unroll
                for (int nt = 0; nt < 4; ++nt)
                    #pragma unroll
                    for (int r = 0; r < 4; ++r) {
                        int row = q*4 + r;
                        if (row < NAG) sh[ep][row*LDB + nt*16+n16] = (__bf16)hC[ep][nt][r];
                    }
        }
    }

    // ---- epilogue: mu only ----
    if (lane < NAG * 3) {
        int i = lane / 3, d = lane - i * 3;
        #pragma unroll
        for (int ep = 0; ep < 2; ++ep) {
            float mu = 0.f;
            #pragma unroll
            for (int v = 0; v < 4; ++v) mu += sx[ep][i*16 + d*4 + v] * w_act[v];
            out[(env0 + ep) * (NAG*3) + lane] = mu;
        }
    }
}

extern "C" void kernel_launch(void* const* d_in, const int* in_sizes, int n_in,
                              void* d_out, int out_size, void* d_ws, size_t ws_size,
                              hipStream_t stream) {
    // inputs: h0,x0,W_embed,b_embed,We1,be1,We2,be2,Wx,bx,Wh1,bh1,Wh2,bh2,w_act,log_std,row,col
    const float* h0   = (const float*)d_in[0];
    const float* x0   = (const float*)d_in[1];
    const float* Wem  = (const float*)d_in[2];
    const float* bem  = (const float*)d_in[3];
    const float* We1  = (const float*)d_in[4];
    const float* be1  = (const float*)d_in[5];
    const float* We2  = (const float*)d_in[6];
    const float* be2  = (const float*)d_in[7];
    const float* Wx   = (const float*)d_in[8];
    const float* bx   = (const float*)d_in[9];
    const float* Wh1  = (const float*)d_in[10];
    const float* bh1  = (const float*)d_in[11];
    const float* Wh2  = (const float*)d_in[12];
    const float* bh2  = (const float*)d_in[13];
    const float* wact = (const float*)d_in[14];
    const float* lstd = (const float*)d_in[15];
    float* out = (float*)d_out;

    if (ws_size >= (size_t)WS_BYTES) {
        prep_frags<<<dim3(WS_FRAGS + 9), dim3(64), 0, stream>>>(
            Wem, We1, We2, Wh1, Wh2, be1, be2, bh1, bh2, bx, (__bf16*)d_ws);
        egnn11<true><<<dim3(NTH / 2), dim3(64), 0, stream>>>(
            h0, x0, Wem, bem, We1, be1, We2, be2, Wx, bx,
            Wh1, bh1, Wh2, bh2, wact, lstd, (const __bf16*)d_ws, out);
    } else {
        egnn11<false><<<dim3(NTH / 2), dim3(64), 0, stream>>>(
            h0, x0, Wem, bem, We1, be1, We2, be2, Wx, bx,
            Wh1, bh1, Wh2, bh2, wact, lstd, nullptr, out);
    }
}